// Round 4
// baseline (297.260 us; speedup 1.0000x reference)
//
#include <hip/hip_runtime.h>
#include <hip/hip_cooperative_groups.h>

namespace cg = cooperative_groups;

#define BATCH 256
#define CH    512
#define HW    196      // 14*14
#define HID   128      // C / RED
#define HW4   49       // HW / 4 (float4 count per row)
#define NBLK  1024
#define NTHR  256
#define NROWS (BATCH * CH)          // 131072
#define NGRP  (NBLK * (NTHR / 16))  // 16384 16-lane groups
#define TOT4  (BATCH * CH * HW4)    // 6,422,528 float4s

typedef float f32x4 __attribute__((ext_vector_type(4)));

// ---------------------------------------------------------------------------
// Fused: pool -> grid.sync -> MLP+rank -> grid.sync -> gate.
// One dispatch: no inter-kernel launch gaps, x stays L3-resident into gate.
// ---------------------------------------------------------------------------
__global__ __launch_bounds__(NTHR, 4) void fused_kernel(
        const f32x4* __restrict__ x4,
        const f32x4* __restrict__ w4,    // dct weights as float4
        const float* __restrict__ w1,
        const float* __restrict__ w2,
        const int*   __restrict__ kt,
        f32x4* __restrict__ out4,
        float* __restrict__ bounded,
        float* __restrict__ raw_out,
        float* __restrict__ mask_out,
        float* __restrict__ s) {
    cg::grid_group grid = cg::this_grid();
    const int tid = threadIdx.x;

    // ---- phase 1: DCT pooling. 16-lane group per row, 8 rows per group ----
    {
        const int g  = tid >> 4;
        const int gl = tid & 15;
        #pragma unroll
        for (int it = 0; it < NROWS / NGRP; ++it) {
            const int row = blockIdx.x * 16 + g + it * NGRP;
            const f32x4* xp = x4 + (size_t)row * HW4;
            const f32x4* wp = w4 + (size_t)(row & (CH - 1)) * HW4;
            float v = 0.0f;
            #pragma unroll
            for (int t = 0; t < 3; ++t) {
                const f32x4 a = xp[gl + 16 * t];
                const f32x4 b = wp[gl + 16 * t];
                v += a.x * b.x + a.y * b.y + a.z * b.z + a.w * b.w;
            }
            if (gl == 0) {
                const f32x4 a = xp[48];
                const f32x4 b = wp[48];
                v += a.x * b.x + a.y * b.y + a.z * b.z + a.w * b.w;
            }
            v += __shfl_xor(v, 8, 64);
            v += __shfl_xor(v, 4, 64);
            v += __shfl_xor(v, 2, 64);
            v += __shfl_xor(v, 1, 64);
            if (gl == 0) s[row] = v;
        }
    }
    grid.sync();

    // ---- phase 2: MLP + tanh + stable top-k rank. Blocks 0..255, 1/batch ----
    __shared__ float s_lds[CH];
    __shared__ float h_lds[HID];
    __shared__ float r_lds[CH];
    if (blockIdx.x < BATCH) {
        const int b = blockIdx.x;
        s_lds[tid]       = s[b * CH + tid];
        s_lds[tid + 256] = s[b * CH + tid + 256];
        __syncthreads();

        if (tid < HID) {
            float h = 0.0f;
            const float* w1p = w1 + (size_t)tid * CH;
            #pragma unroll 4
            for (int j = 0; j < CH; ++j) h += s_lds[j] * w1p[j];
            h_lds[tid] = fmaxf(h, 0.0f);
        }
        __syncthreads();

        #pragma unroll
        for (int c = tid; c < CH; c += NTHR) {
            float r = 0.0f;
            const float* w2p = w2 + (size_t)c * HID;
            #pragma unroll 4
            for (int j = 0; j < HID; ++j) r += h_lds[j] * w2p[j];
            r_lds[c] = r;
            raw_out[b * CH + c] = r;
            bounded[b * CH + c] = tanhf(r);
        }
        __syncthreads();

        const int k = kt[b];
        #pragma unroll
        for (int c = tid; c < CH; c += NTHR) {
            const float r = r_lds[c];
            int cnt = 0;
            #pragma unroll 8
            for (int j = 0; j < CH; ++j) {
                const float rj = r_lds[j];
                cnt += (rj > r) || (rj == r && j < c);
            }
            mask_out[b * CH + c] = (cnt < k) ? 1.0f : 0.0f;
        }
    }
    grid.sync();

    // ---- phase 3: gate. m is exactly 0 or 1: pass-through or zero-store ----
    {
        const int stride = NBLK * NTHR;
        for (int i = blockIdx.x * NTHR + tid; i < TOT4; i += stride) {
            const int row = i / HW4;             // magic-mul division
            const float m = mask_out[row];
            f32x4 v;
            if (m != 0.0f) {
                v = x4[i];
            } else {
                v = (f32x4)(0.0f);
            }
            __builtin_nontemporal_store(v, &out4[i]);
        }
    }
}

extern "C" void kernel_launch(void* const* d_in, const int* in_sizes, int n_in,
                              void* d_out, int out_size, void* d_ws, size_t ws_size,
                              hipStream_t stream) {
    const f32x4* x4   = (const f32x4*)d_in[0];   // [256,512,14,14]
    const f32x4* w4   = (const f32x4*)d_in[1];   // [512,14,14]
    const float* w1   = (const float*)d_in[2];   // [128,512]
    const float* w2   = (const float*)d_in[3];   // [512,128]
    const int*   kt   = (const int*)d_in[4];     // [256] (int32: jax x64 off)

    float* out     = (float*)d_out;                          // 256*512*196
    float* bounded = out + (size_t)BATCH * CH * HW;
    float* raw     = bounded + BATCH * CH;
    float* mask    = raw + BATCH * CH;
    float* s       = mask + BATCH * CH;
    f32x4* out4    = (f32x4*)out;

    void* args[] = {(void*)&x4, (void*)&w4, (void*)&w1, (void*)&w2, (void*)&kt,
                    (void*)&out4, (void*)&bounded, (void*)&raw, (void*)&mask, (void*)&s};
    hipLaunchCooperativeKernel((const void*)fused_kernel, dim3(NBLK), dim3(NTHR),
                               args, 0, stream);
}

// Round 5
// 75.742 us; speedup vs baseline: 3.9247x; 3.9247x over previous
//
#include <hip/hip_runtime.h>

#define BATCH 256
#define CH    512
#define HW    196      // 14*14
#define HID   128      // C / RED
#define HW4   49       // float4s per (b,c) row
#define ROW4  (CH * HW4)   // 25088 float4s per batch
#define NTHR  1024

typedef float f32x4 __attribute__((ext_vector_type(4)));

// One block per batch image. Pool -> MLP -> rank -> gate, all in-block
// (__syncthreads only; per-batch dependency chain needs no grid sync).
// Gate re-reads x[b] which this block just streamed -> L3 hit.
__global__ __launch_bounds__(NTHR) void fca_kernel(
        const f32x4* __restrict__ x4,
        const f32x4* __restrict__ w4,    // dct weight, [CH][49] f4
        const float* __restrict__ w1,    // [HID][CH]
        const float* __restrict__ w2,    // [CH][HID]
        const int*   __restrict__ kt,    // [BATCH]
        f32x4* __restrict__ out4,
        float* __restrict__ bounded,
        float* __restrict__ raw_out,
        float* __restrict__ mask_out,
        float* __restrict__ s_out) {
    __shared__ float s_lds[CH];
    __shared__ float h_lds[HID];
    __shared__ float r_lds[CH];
    __shared__ float m_lds[CH];

    const int b   = blockIdx.x;
    const int tid = threadIdx.x;
    const f32x4* xb = x4 + (size_t)b * ROW4;
    const int k = kt[b];

    // ---- phase 1: DCT pooling. 64 groups of 16 lanes; 8 channels/group ----
    {
        const int g  = tid >> 4;          // 0..63
        const int gl = tid & 15;
        #pragma unroll
        for (int it = 0; it < CH / 64; ++it) {
            const int c = g + it * 64;
            const f32x4* xp = xb + (size_t)c * HW4;
            const f32x4* wp = w4 + (size_t)c * HW4;
            float v = 0.0f;
            #pragma unroll
            for (int t = 0; t < 3; ++t) {
                const f32x4 a = xp[gl + 16 * t];
                const f32x4 w = wp[gl + 16 * t];
                v += a.x * w.x + a.y * w.y + a.z * w.z + a.w * w.w;
            }
            if (gl == 0) {
                const f32x4 a = xp[48];
                const f32x4 w = wp[48];
                v += a.x * w.x + a.y * w.y + a.z * w.z + a.w * w.w;
            }
            v += __shfl_xor(v, 8, 64);
            v += __shfl_xor(v, 4, 64);
            v += __shfl_xor(v, 2, 64);
            v += __shfl_xor(v, 1, 64);
            if (gl == 0) { s_lds[c] = v; s_out[b * CH + c] = v; }
        }
    }
    __syncthreads();

    // ---- phase 2a: hidden = relu(s @ w1.T); 8 threads per hidden unit ----
    {
        const int u  = tid >> 3;          // 0..127
        const int j0 = tid & 7;
        float h = 0.0f;
        const float* w1p = w1 + (size_t)u * CH;
        for (int j = j0; j < CH; j += 8) h += s_lds[j] * w1p[j];
        h += __shfl_xor(h, 4, 64);
        h += __shfl_xor(h, 2, 64);
        h += __shfl_xor(h, 1, 64);
        if (j0 == 0) h_lds[u] = fmaxf(h, 0.0f);
    }
    __syncthreads();

    // ---- phase 2b: raw[c] = h . w2[c]; 2 threads per channel.
    // Summation structure identical for every c -> exact ties preserved. ----
    {
        const int c    = tid >> 1;        // 0..511
        const int half = tid & 1;
        float r = 0.0f;
        const float* w2p = w2 + (size_t)c * HID + half * 64;
        #pragma unroll 4
        for (int j = 0; j < 64; ++j) r += h_lds[half * 64 + j] * w2p[j];
        const float other = __shfl_xor(r, 1, 64);
        const float rt = (half == 0) ? (r + other) : (other + r);
        if (half == 0) {
            r_lds[c] = rt;
            raw_out[b * CH + c] = rt;
            bounded[b * CH + c] = tanhf(rt);
        }
    }
    __syncthreads();

    // ---- phase 2c: stable descending rank vs k -> mask ----
    {
        const int c    = tid >> 1;
        const int half = tid & 1;
        const float r = r_lds[c];
        int cnt = 0;
        #pragma unroll 8
        for (int j = half * 256; j < half * 256 + 256; ++j) {
            const float rj = r_lds[j];
            cnt += (rj > r) || (rj == r && j < c);
        }
        cnt += __shfl_xor(cnt, 1, 64);
        if (half == 0) {
            const float m = (cnt < k) ? 1.0f : 0.0f;
            m_lds[c] = m;
            mask_out[b * CH + c] = m;
        }
    }
    __syncthreads();

    // ---- phase 3: gate. x[b] is L3-hot from phase 1; skip reads for m==0 ----
    {
        f32x4* ob = out4 + (size_t)b * ROW4;
        for (int i = tid; i < ROW4; i += NTHR) {
            const int c = i / HW4;        // magic-mul division
            f32x4 v;
            if (m_lds[c] != 0.0f) v = xb[i];
            else                  v = (f32x4)(0.0f);
            __builtin_nontemporal_store(v, &ob[i]);
        }
    }
}

extern "C" void kernel_launch(void* const* d_in, const int* in_sizes, int n_in,
                              void* d_out, int out_size, void* d_ws, size_t ws_size,
                              hipStream_t stream) {
    const f32x4* x4   = (const f32x4*)d_in[0];   // [256,512,14,14]
    const f32x4* w4   = (const f32x4*)d_in[1];   // [512,14,14]
    const float* w1   = (const float*)d_in[2];   // [128,512]
    const float* w2   = (const float*)d_in[3];   // [512,128]
    const int*   kt   = (const int*)d_in[4];     // [256]

    float* out     = (float*)d_out;                          // 256*512*196
    float* bounded = out + (size_t)BATCH * CH * HW;
    float* raw     = bounded + BATCH * CH;
    float* mask    = raw + BATCH * CH;
    float* s       = mask + BATCH * CH;

    fca_kernel<<<BATCH, NTHR, 0, stream>>>(
        x4, w4, w1, w2, kt, (f32x4*)out, bounded, raw, mask, s);
}